// Round 5
// baseline (265.062 us; speedup 1.0000x reference)
//
#include <hip/hip_runtime.h>
#include <hip/hip_fp16.h>
#include <math.h>

typedef _Float16 h2_t __attribute__((ext_vector_type(2)));
typedef _Float16 h4_t __attribute__((ext_vector_type(4)));
typedef _Float16 h8_t __attribute__((ext_vector_type(8)));
typedef float f4_t __attribute__((ext_vector_type(4)));
typedef float f8_t __attribute__((ext_vector_type(8)));

#define PRE_BLOCKS 512
#define SB 512          // scatter/hist blocks (edge chunking)
#define NBUK_PAD 800    // padded bucket count; real buckets = (N+63)>>6 <= 782

__device__ inline h8_t load8f_to_h8(const float* p) {
    float4 a = *(const float4*)p;
    float4 b = *(const float4*)(p + 4);
    h8_t r;
    r[0] = (_Float16)a.x; r[1] = (_Float16)a.y; r[2] = (_Float16)a.z; r[3] = (_Float16)a.w;
    r[4] = (_Float16)b.x; r[5] = (_Float16)b.y; r[6] = (_Float16)b.z; r[7] = (_Float16)b.w;
    return r;
}

__device__ inline h4_t load4f_to_h4(const float* p) {
    float4 a = *(const float4*)p;
    h4_t r;
    r[0] = (_Float16)a.x; r[1] = (_Float16)a.y; r[2] = (_Float16)a.z; r[3] = (_Float16)a.w;
    return r;
}

__device__ inline float dot8h(h8_t a, h8_t b, float s) {
    s = __builtin_amdgcn_fdot2(__builtin_shufflevector(a, a, 0, 1),
                               __builtin_shufflevector(b, b, 0, 1), s, false);
    s = __builtin_amdgcn_fdot2(__builtin_shufflevector(a, a, 2, 3),
                               __builtin_shufflevector(b, b, 2, 3), s, false);
    s = __builtin_amdgcn_fdot2(__builtin_shufflevector(a, a, 4, 5),
                               __builtin_shufflevector(b, b, 4, 5), s, false);
    s = __builtin_amdgcn_fdot2(__builtin_shufflevector(a, a, 6, 7),
                               __builtin_shufflevector(b, b, 6, 7), s, false);
    return s;
}

__device__ inline float dot4h(h4_t a, h4_t b, float s) {
    s = __builtin_amdgcn_fdot2(__builtin_shufflevector(a, a, 0, 1),
                               __builtin_shufflevector(b, b, 0, 1), s, false);
    s = __builtin_amdgcn_fdot2(__builtin_shufflevector(a, a, 2, 3),
                               __builtin_shufflevector(b, b, 2, 3), s, false);
    return s;
}

__device__ inline float elu1(float v) { return v > 0.f ? v : __expf(v) - 1.f; }

struct MA {
    const float* x;
    const float* eattr;
    const int* ei;
    const float *w1l, *b1l, *w1r, *b1r, *w1e, *att1, *bias1;
    const float *w2l, *b2l, *w2r, *b2r, *w2e, *att2, *bias2;
    const float *wc, *bc;
    float* out;
    _Float16 *xh, *xl1h, *xr1h, *h1h, *xl2h, *xr2h;
    _Float16 *p1l, *p1r, *p2l, *p2r;
    int *deg, *offb;
    unsigned* parth;      // SB x NBUK_PAD partial hist; overwritten in-place as scatter bases
    unsigned *tstart, *tot;
    unsigned* smeanq;
    unsigned* tmp;        // 4B packed: src[0:15] | q[16:23] | loc[24:29]
    unsigned* flags;
    float* part;
    unsigned* edges;
    int N, E, NW, NBK, CE;
    float invE;
};

// ---- phase helpers -------------------------------------------------------

__device__ inline void phase_packw(const MA& a, int g) {
    const float* W;
    _Float16* P;
    int M, lg;
    if (g < 2048)      { W = a.w1l; P = a.p1l; M = 128; lg = g; }
    else if (g < 4096) { W = a.w1r; P = a.p1r; M = 128; lg = g - 2048; }
    else if (g < 5120) { W = a.w2l; P = a.p2l; M = 64;  lg = g - 4096; }
    else               { W = a.w2r; P = a.p2r; M = 64;  lg = g - 5120; }
    int ln = lg & 63;
    int s = (lg >> 6) & 3;
    int tt = lg >> 8;
    int m = ln & 15, quad = ln >> 4;
    h8_t v;
#pragma unroll
    for (int j = 0; j < 8; ++j)
        v[j] = (_Float16)W[(size_t)(s * 32 + quad * 8 + j) * M + tt * 16 + m];
    *(h8_t*)(P + (size_t)lg * 8) = v;
}

template <int NT>
__device__ inline void phase_mm_tile(const MA& a, const _Float16* X, int rt, int lane,
                                     const _Float16* Pl, const float* bl, _Float16* Yl,
                                     const _Float16* Pr, const float* br, _Float16* Yr) {
    int nrow = lane & 15, quad = lane >> 4;
    int row = rt * 16 + nrow;
    if (row >= a.N) return;
    const _Float16* xp = X + (size_t)row * 128 + quad * 8;
    h8_t bf0 = *(const h8_t*)(xp);
    h8_t bf1 = *(const h8_t*)(xp + 32);
    h8_t bf2 = *(const h8_t*)(xp + 64);
    h8_t bf3 = *(const h8_t*)(xp + 96);
#pragma unroll
    for (int w = 0; w < 2; ++w) {
        const _Float16* P = w ? Pr : Pl;
        const float* bias = w ? br : bl;
        _Float16* Y = w ? Yr : Yl;
#pragma unroll
        for (int t2 = 0; t2 < NT; ++t2) {
            f4_t acc = {0.f, 0.f, 0.f, 0.f};
            const _Float16* pb = P + (size_t)t2 * 2048 + (size_t)lane * 8;
            acc = __builtin_amdgcn_mfma_f32_16x16x32_f16(*(const h8_t*)pb, bf0, acc, 0, 0, 0);
            acc = __builtin_amdgcn_mfma_f32_16x16x32_f16(*(const h8_t*)(pb + 512), bf1, acc, 0, 0, 0);
            acc = __builtin_amdgcn_mfma_f32_16x16x32_f16(*(const h8_t*)(pb + 1024), bf2, acc, 0, 0, 0);
            acc = __builtin_amdgcn_mfma_f32_16x16x32_f16(*(const h8_t*)(pb + 1536), bf3, acc, 0, 0, 0);
            float4 bv = *(const float4*)(bias + t2 * 16 + quad * 4);
            h4_t o;
            o[0] = (_Float16)(acc[0] + bv.x);
            o[1] = (_Float16)(acc[1] + bv.y);
            o[2] = (_Float16)(acc[2] + bv.z);
            o[3] = (_Float16)(acc[3] + bv.w);
            *(h4_t*)(Y + (size_t)row * (NT * 16) + t2 * 16 + quad * 4) = o;
        }
    }
}

// ---- k_pre: zero flags, x->fp16, eattr partials, per-chunk bucket hist;
// tail blocks pack weights ------------------------------------------------

__global__ __launch_bounds__(256) void k_pre(MA a) {
    if (blockIdx.x >= PRE_BLOCKS) {
        int g = (blockIdx.x - PRE_BLOCKS) * 256 + threadIdx.x;
        if (g < 6144) phase_packw(a, g);
        return;
    }
    __shared__ unsigned bh[NBUK_PAD];
    __shared__ float sd[4];
    int tx = threadIdx.x;
    for (int j = tx; j < NBUK_PAD; j += 256) bh[j] = 0u;

    int t = blockIdx.x * 256 + tx;
    const int stride = PRE_BLOCKS * 256;
    for (int i = t; i < NBUK_PAD; i += stride) a.flags[i] = 0u;
    int nchunk = (a.N * 128) >> 3;
    for (int i = t; i < nchunk; i += stride) {
        h8_t v = load8f_to_h8(a.x + (size_t)i * 8);
        *(h8_t*)(a.xh + (size_t)i * 8) = v;
    }
    float s = 0.f;
    for (int i = t; i < a.E; i += stride) s += a.eattr[i];
    for (int o = 1; o < 64; o <<= 1) s += __shfl_xor(s, o, 64);
    if ((tx & 63) == 0) sd[tx >> 6] = s;
    __syncthreads();  // bh zeroed + sd published
    if (tx == 0) a.part[blockIdx.x] = sd[0] + sd[1] + sd[2] + sd[3];

    // chunked bucket histogram (must match k_scatter's chunking exactly)
    int e0 = blockIdx.x * a.CE, e1 = min(e0 + a.CE, a.E);
    for (int e = e0 + tx; e < e1; e += 256)
        atomicAdd(&bh[((unsigned)a.ei[a.E + e]) >> 6], 1u);
    __syncthreads();
    for (int j = tx; j < NBUK_PAD; j += 256)
        a.parth[(size_t)blockIdx.x * NBUK_PAD + j] = bh[j];
}

// ---- k_colscan: per bucket, scan the 512 block-partials (column of parth),
// decoupled lookback over buckets -> bucket starts; rewrite parth in place
// as absolute tmp-scatter bases. Block 0 also reduces eattr mean. ----------

__global__ __launch_bounds__(512, 1) void k_colscan(MA a) {
    __shared__ unsigned lds[512];
    __shared__ unsigned sbase;
    __shared__ float sd[8];
    int tx = threadIdx.x;
    int b = blockIdx.x;
    unsigned v = a.parth[(size_t)tx * NBUK_PAD + b];
    lds[tx] = v;
    __syncthreads();
    for (int o = 1; o < 512; o <<= 1) {
        unsigned u = (tx >= o) ? lds[tx - o] : 0u;
        __syncthreads();
        lds[tx] += u;
        __syncthreads();
    }
    unsigned T = lds[511];
    unsigned excl = lds[tx] - v;
    if (tx == 0) {
        unsigned run = 0;
        if (b == 0) {
            atomicExch(&a.flags[0], (2u << 30) | T);
        } else {
            atomicExch(&a.flags[b], (1u << 30) | T);
            int j = b - 1;
            while (true) {
                unsigned f = atomicAdd(&a.flags[j], 0u);
                unsigned st = f >> 30;
                if (st == 0u) continue;
                run += f & 0x3FFFFFFFu;
                if (st == 2u) break;
                --j;
            }
            atomicExch(&a.flags[b], (2u << 30) | (run + T));
        }
        a.tstart[b] = run;
        a.tot[b] = T;
        sbase = run;
    }
    __syncthreads();
    a.parth[(size_t)tx * NBUK_PAD + b] = sbase + excl;

    if (b == 0) {
        float s = a.part[tx];  // PRE_BLOCKS == 512 partials
        for (int o = 1; o < 64; o <<= 1) s += __shfl_xor(s, o, 64);
        if ((tx & 63) == 0) sd[tx >> 6] = s;
        __syncthreads();
        if (tx == 0) {
            float m = 0.f;
#pragma unroll
            for (int k = 0; k < 8; ++k) m += sd[k];
            a.smeanq[0] = (unsigned)__float2int_rn(m * a.invE * 255.f);
        }
    }
}

// ---- k_scatter: blocks [0,NW) = layer-1 GEMM; blocks [NW,NW+SB) scatter
// edges into coarse-bucket regions of tmp via LDS cursors (zero global
// atomics; bases from colscan make slots collision-free across blocks).
// tmp entry packed in 4B: src[0:15] | q[16:23] | loc[24:29] (N < 65536). --

__global__ __launch_bounds__(256) void k_scatter(MA a) {
    int bid = blockIdx.x;
    if (bid < a.NW) {
        int wid = bid * 4 + (threadIdx.x >> 6);
        int ntile = (a.N + 15) / 16;
        if (wid < ntile)
            phase_mm_tile<8>(a, a.xh, wid, threadIdx.x & 63,
                             a.p1l, a.b1l, a.xl1h, a.p1r, a.b1r, a.xr1h);
        return;
    }
    __shared__ unsigned cur[NBUK_PAD];
    int s = bid - a.NW;
    int tx = threadIdx.x;
    for (int j = tx; j < NBUK_PAD; j += 256)
        cur[j] = a.parth[(size_t)s * NBUK_PAD + j];
    __syncthreads();
    int e0 = s * a.CE, e1 = min(e0 + a.CE, a.E);
    for (int e = e0 + tx; e < e1; e += 256) {
        int d = a.ei[a.E + e];
        unsigned src = (unsigned)a.ei[e];
        unsigned q = (unsigned)__float2int_rn(a.eattr[e] * 255.f);
        unsigned pos = atomicAdd(&cur[d >> 6], 1u);
        a.tmp[pos] = src | (q << 16) | ((unsigned)(d & 63) << 24);
    }
}

// ---- k_fine: per bucket (64 contiguous nodes): local hist + wave scan ->
// exact CSR offsets (no global scan needed), write self-loops + edges. ----

__global__ __launch_bounds__(256) void k_fine(MA a) {
    __shared__ int hist[64];
    __shared__ unsigned cur[64];
    __shared__ unsigned sm;
    int b = blockIdx.x;
    int tx = threadIdx.x;
    int n0 = b << 6;
    int nn = min(64, a.N - n0);
    unsigned ts = a.tstart[b], T = a.tot[b];
    if (tx < 64) hist[tx] = 0;
    if (tx == 0) sm = a.smeanq[0];
    __syncthreads();
    for (unsigned i = tx; i < T; i += 256) {
        unsigned v = a.tmp[ts + i];
        atomicAdd(&hist[(int)(v >> 24)], 1);
    }
    __syncthreads();
    if (tx < 64) {
        int deg1 = hist[tx] + 1;
        int vsc = deg1;
#pragma unroll
        for (int o = 1; o < 64; o <<= 1) {
            int u = __shfl_up(vsc, o, 64);
            if (tx >= o) vsc += u;
        }
        int off = (int)ts + n0 + (vsc - deg1);  // ts + 64*b accounts for prior self-loops
        if (tx < nn) {
            a.offb[n0 + tx] = off;
            a.deg[n0 + tx] = deg1;
            a.edges[off] = (unsigned)(n0 + tx) | (sm << 24);
        }
        cur[tx] = (unsigned)(off + 1);
    }
    __syncthreads();
    for (unsigned i = tx; i < T; i += 256) {
        unsigned v = a.tmp[ts + i];
        int loc = (int)(v >> 24);
        unsigned pos = atomicAdd(&cur[loc], 1u);
        a.edges[pos] = (v & 0xFFFFu) | (((v >> 16) & 0xFFu) << 24);
    }
}

// ---- k_node1: layer-1 node pass. 16 lanes per node, software-pipelined
// double buffer: per 8 edges {loadB, computeA, loadA(next), computeB} so
// each group's edge-word + gather loads are issued one full compute phase
// before consumption (hides ~900cy chain; R3 showed VALUBusy 49% = latency
// bound). No register rotation (named A/B buffers). ------------------------

__global__ __launch_bounds__(256) void k_node1(MA a) {
    int tid = threadIdx.x;
    int q = tid & 15;
    int node = blockIdx.x * 16 + (tid >> 4);
    if (node >= a.N) return;
    unsigned cb = (unsigned)(q * 16);  // byte offset of this lane's 8 halves

    h8_t xrv = *(const h8_t*)((const char*)a.xr1h + ((unsigned)node << 8) + cb);
    h8_t wev = load8f_to_h8(a.w1e + q * 8);
    h8_t atv = load8f_to_h8(a.att1 + q * 8);
    const unsigned* ep = a.edges + a.offb[node];
    int deg1 = a.deg[node];
    int last = deg1 - 1;
    const char* xb = (const char*)a.xl1h;

    float l = 0.f;
    f8_t acc = {0.f, 0.f, 0.f, 0.f, 0.f, 0.f, 0.f, 0.f};

    auto GA = [&](unsigned p) -> h8_t {
        return *(const h8_t*)(xb + (((p & 0x00FFFFFFu) << 8) | cb));
    };
    auto LOADG = [&](int i, unsigned& p0, unsigned& p1, unsigned& p2, unsigned& p3,
                     h8_t& x0, h8_t& x1, h8_t& x2, h8_t& x3) {
        p0 = ep[i];
        p1 = ep[min(i + 1, last)];
        p2 = ep[min(i + 2, last)];
        p3 = ep[min(i + 3, last)];
        x0 = GA(p0); x1 = GA(p1); x2 = GA(p2); x3 = GA(p3);
    };
    auto COMPG = [&](int i, unsigned p0, unsigned p1, unsigned p2, unsigned p3,
                     h8_t x0, h8_t x1, h8_t x2, h8_t x3) {
        float e0 = (float)(p0 >> 24) * (1.f / 255.f);
        float e1 = (float)(p1 >> 24) * (1.f / 255.f);
        float e2 = (float)(p2 >> 24) * (1.f / 255.f);
        float e3 = (float)(p3 >> 24) * (1.f / 255.f);
        h8_t z0 = x0 + xrv + wev * (_Float16)e0;
        z0 = __builtin_elementwise_max(z0, z0 * (_Float16)0.2f);
        float sc0 = dot8h(z0, atv, 0.f);
        h8_t z1 = x1 + xrv + wev * (_Float16)e1;
        z1 = __builtin_elementwise_max(z1, z1 * (_Float16)0.2f);
        float sc1 = dot8h(z1, atv, 0.f);
        h8_t z2 = x2 + xrv + wev * (_Float16)e2;
        z2 = __builtin_elementwise_max(z2, z2 * (_Float16)0.2f);
        float sc2 = dot8h(z2, atv, 0.f);
        h8_t z3 = x3 + xrv + wev * (_Float16)e3;
        z3 = __builtin_elementwise_max(z3, z3 * (_Float16)0.2f);
        float sc3 = dot8h(z3, atv, 0.f);
        sc0 += __shfl_xor(sc0, 1, 64); sc0 += __shfl_xor(sc0, 2, 64);
        sc1 += __shfl_xor(sc1, 1, 64); sc1 += __shfl_xor(sc1, 2, 64);
        sc2 += __shfl_xor(sc2, 1, 64); sc2 += __shfl_xor(sc2, 2, 64);
        sc3 += __shfl_xor(sc3, 1, 64); sc3 += __shfl_xor(sc3, 2, 64);
        float pA = __expf(fminf(sc0, 60.f));
        float pB = (i + 1 < deg1) ? __expf(fminf(sc1, 60.f)) : 0.f;
        float pC = (i + 2 < deg1) ? __expf(fminf(sc2, 60.f)) : 0.f;
        float pD = (i + 3 < deg1) ? __expf(fminf(sc3, 60.f)) : 0.f;
        l += (pA + pB) + (pC + pD);
#pragma unroll
        for (int k = 0; k < 8; ++k)
            acc[k] = fmaf(pA, (float)x0[k],
                     fmaf(pB, (float)x1[k],
                     fmaf(pC, (float)x2[k], fmaf(pD, (float)x3[k], acc[k]))));
    };

    unsigned pa0, pa1, pa2, pa3, pb0, pb1, pb2, pb3;
    h8_t xa0, xa1, xa2, xa3, xb0, xb1, xb2, xb3;
    LOADG(0, pa0, pa1, pa2, pa3, xa0, xa1, xa2, xa3);
    for (int i = 0; i < deg1; i += 8) {
        if (i + 4 < deg1) LOADG(i + 4, pb0, pb1, pb2, pb3, xb0, xb1, xb2, xb3);
        COMPG(i, pa0, pa1, pa2, pa3, xa0, xa1, xa2, xa3);
        if (i + 8 < deg1) LOADG(i + 8, pa0, pa1, pa2, pa3, xa0, xa1, xa2, xa3);
        if (i + 4 < deg1) COMPG(i + 4, pb0, pb1, pb2, pb3, xb0, xb1, xb2, xb3);
    }

    float inv = 1.f / l;
    float4 b0 = *(const float4*)(a.bias1 + q * 8);
    float4 b1 = *(const float4*)(a.bias1 + q * 8 + 4);
    float bb[8] = {b0.x, b0.y, b0.z, b0.w, b1.x, b1.y, b1.z, b1.w};
    h8_t o;
#pragma unroll
    for (int k = 0; k < 8; ++k) o[k] = (_Float16)elu1(fmaf(acc[k], inv, bb[k]));
    *(h8_t*)((char*)a.h1h + ((unsigned)node << 8) + cb) = o;
}

// ---- k_mm4: layer-2 MFMA GEMM --------------------------------------------

__global__ __launch_bounds__(256) void k_mm4(MA a) {
    int wid = blockIdx.x * 4 + (threadIdx.x >> 6);
    int ntile = (a.N + 15) / 16;
    if (wid >= ntile) return;
    phase_mm_tile<4>(a, a.h1h, wid, threadIdx.x & 63,
                     a.p2l, a.b2l, a.xl2h, a.p2r, a.b2r, a.xr2h);
}

// ---- k_node2: layer-2 node pass + fused classifier; same double-buffer
// software pipeline as k_node1. --------------------------------------------

__global__ __launch_bounds__(256) void k_node2(MA a) {
    __shared__ float h2s[16][33];
    int tid = threadIdx.x;
    int lane = tid & 63;
    int wib = tid >> 6;
    int sub = lane >> 4;
    int r = lane & 15;
    int nloc = wib * 4 + sub;
    int node = blockIdx.x * 16 + nloc;
    int c0 = r * 4;

    if (node < a.N) {
        h4_t xrv = *(const h4_t*)(a.xr2h + (size_t)node * 64 + c0);
        h4_t wev = load4f_to_h4(a.w2e + c0);
        h4_t atv = load4f_to_h4(a.att2 + c0);
        const unsigned* ep = a.edges + a.offb[node];
        int deg1 = a.deg[node];
        int last = deg1 - 1;
        const char* xb = (const char*)a.xl2h;
        unsigned cb = (unsigned)(c0 * 2);
        float l = 0.f;
        float acc[4] = {0.f, 0.f, 0.f, 0.f};

        auto GA = [&](unsigned p) -> h4_t {
            return *(const h4_t*)(xb + (((p & 0x00FFFFFFu) << 7) | cb));
        };
        auto LOADG = [&](int i, unsigned& p0, unsigned& p1, unsigned& p2, unsigned& p3,
                         h4_t& x0, h4_t& x1, h4_t& x2, h4_t& x3) {
            p0 = ep[i];
            p1 = ep[min(i + 1, last)];
            p2 = ep[min(i + 2, last)];
            p3 = ep[min(i + 3, last)];
            x0 = GA(p0); x1 = GA(p1); x2 = GA(p2); x3 = GA(p3);
        };
        auto CEDGE = [&](int idx, unsigned p, h4_t xv) {
            float ea = (float)(p >> 24) * (1.f / 255.f);
            h4_t z = xv + xrv + wev * (_Float16)ea;
            z = __builtin_elementwise_max(z, z * (_Float16)0.2f);
            float sc = dot4h(z, atv, 0.f);
            sc += __shfl_xor(sc, 1, 64);
            sc += __shfl_xor(sc, 2, 64);
            sc += __shfl_xor(sc, 4, 64);
            float pp = (idx < deg1) ? __expf(fminf(sc, 60.f)) : 0.f;
            l += pp;
#pragma unroll
            for (int k = 0; k < 4; ++k) acc[k] = fmaf(pp, (float)xv[k], acc[k]);
        };

        unsigned pa0, pa1, pa2, pa3, pb0, pb1, pb2, pb3;
        h4_t xa0, xa1, xa2, xa3, xb0, xb1, xb2, xb3;
        LOADG(0, pa0, pa1, pa2, pa3, xa0, xa1, xa2, xa3);
        for (int i = 0; i < deg1; i += 8) {
            if (i + 4 < deg1) LOADG(i + 4, pb0, pb1, pb2, pb3, xb0, xb1, xb2, xb3);
            CEDGE(i, pa0, xa0); CEDGE(i + 1, pa1, xa1);
            CEDGE(i + 2, pa2, xa2); CEDGE(i + 3, pa3, xa3);
            if (i + 8 < deg1) LOADG(i + 8, pa0, pa1, pa2, pa3, xa0, xa1, xa2, xa3);
            if (i + 4 < deg1) {
                CEDGE(i + 4, pb0, xb0); CEDGE(i + 5, pb1, xb1);
                CEDGE(i + 6, pb2, xb2); CEDGE(i + 7, pb3, xb3);
            }
        }

        float inv = 1.f / l;
#pragma unroll
        for (int k = 0; k < 4; ++k) {
            float norm = acc[k] * inv;
            float other = __shfl_xor(norm, 8, 64);
            float v = 0.5f * (norm + other);
            if (r < 8) h2s[nloc][c0 + k] = elu1(v + a.bias2[c0 + k]);
        }
    }
    __syncthreads();
    if (tid < 128) {
        int n = tid >> 3, j = tid & 7;
        int gnode = blockIdx.x * 16 + n;
        if (gnode < a.N) {
            float acc = a.bc[j];
#pragma unroll 8
            for (int d = 0; d < 32; ++d) acc = fmaf(h2s[n][d], a.wc[d * 8 + j], acc);
            a.out[(size_t)gnode * 8 + j] = acc;
        }
    }
}

// ---- launch --------------------------------------------------------------

extern "C" void kernel_launch(void* const* d_in, const int* in_sizes, int n_in,
                              void* d_out, int out_size, void* d_ws, size_t ws_size,
                              hipStream_t stream) {
    const int N = in_sizes[0] / 128;
    const int E = in_sizes[2];
    const int tot = E + N;

    char* ws = (char*)d_ws;
    size_t o = 0;
    auto alloc = [&](size_t bytes) -> void* {
        void* p = ws + o;
        o += (bytes + 255) & ~(size_t)255;
        return p;
    };
    MA a;
    a.x     = (const float*)d_in[0];
    a.ei    = (const int*)d_in[1];
    a.eattr = (const float*)d_in[2];
    a.w1l = (const float*)d_in[3];  a.b1l = (const float*)d_in[4];
    a.w1r = (const float*)d_in[5];  a.b1r = (const float*)d_in[6];
    a.w1e = (const float*)d_in[7];  a.att1 = (const float*)d_in[8];
    a.bias1 = (const float*)d_in[9];
    a.w2l = (const float*)d_in[10]; a.b2l = (const float*)d_in[11];
    a.w2r = (const float*)d_in[12]; a.b2r = (const float*)d_in[13];
    a.w2e = (const float*)d_in[14]; a.att2 = (const float*)d_in[15];
    a.bias2 = (const float*)d_in[16];
    a.wc = (const float*)d_in[17];  a.bc = (const float*)d_in[18];
    a.out = (float*)d_out;

    a.xh   = (_Float16*)alloc((size_t)N * 128 * 2);
    a.xl1h = (_Float16*)alloc((size_t)N * 128 * 2);
    a.xr1h = (_Float16*)alloc((size_t)N * 128 * 2);
    a.h1h  = (_Float16*)alloc((size_t)N * 128 * 2);
    a.xl2h = (_Float16*)alloc((size_t)N * 64 * 2);
    a.xr2h = (_Float16*)alloc((size_t)N * 64 * 2);
    a.p1l  = (_Float16*)alloc(128 * 128 * 2);
    a.p1r  = (_Float16*)alloc(128 * 128 * 2);
    a.p2l  = (_Float16*)alloc(128 * 64 * 2);
    a.p2r  = (_Float16*)alloc(128 * 64 * 2);
    a.deg  = (int*)alloc((size_t)N * 4);
    a.offb = (int*)alloc((size_t)N * 4);
    a.parth  = (unsigned*)alloc((size_t)SB * NBUK_PAD * 4);
    a.tstart = (unsigned*)alloc(NBUK_PAD * 4);
    a.tot    = (unsigned*)alloc(NBUK_PAD * 4);
    a.smeanq = (unsigned*)alloc(256);
    a.flags  = (unsigned*)alloc(1024 * 4);
    a.part   = (float*)alloc(PRE_BLOCKS * 4);
    a.tmp    = (unsigned*)alloc((size_t)E * 4);
    a.edges  = (unsigned*)alloc((size_t)tot * 4);
    a.N = N;
    a.E = E;
    a.NW = (N + 63) / 64;
    a.NBK = (N + 63) >> 6;
    a.CE = (E + SB - 1) / SB;
    a.invE = 1.0f / (float)E;

    k_pre<<<PRE_BLOCKS + 24, 256, 0, stream>>>(a);
    k_colscan<<<a.NBK, 512, 0, stream>>>(a);
    k_scatter<<<a.NW + SB, 256, 0, stream>>>(a);
    k_fine<<<a.NBK, 256, 0, stream>>>(a);
    k_node1<<<(N + 15) / 16, 256, 0, stream>>>(a);
    k_mm4<<<(N + 63) / 64, 256, 0, stream>>>(a);
    k_node2<<<(N + 15) / 16, 256, 0, stream>>>(a);
}

// Round 6
// 239.297 us; speedup vs baseline: 1.1077x; 1.1077x over previous
//
#include <hip/hip_runtime.h>
#include <hip/hip_fp16.h>
#include <math.h>

typedef _Float16 h2_t __attribute__((ext_vector_type(2)));
typedef _Float16 h4_t __attribute__((ext_vector_type(4)));
typedef _Float16 h8_t __attribute__((ext_vector_type(8)));
typedef float f4_t __attribute__((ext_vector_type(4)));
typedef float f8_t __attribute__((ext_vector_type(8)));

#define PRE_BLOCKS 512
#define SB 512          // scatter/hist blocks (edge chunking)
#define NBUK_PAD 800    // padded bucket count; real buckets = (N+63)>>6 <= 782

__device__ inline h8_t load8f_to_h8(const float* p) {
    float4 a = *(const float4*)p;
    float4 b = *(const float4*)(p + 4);
    h8_t r;
    r[0] = (_Float16)a.x; r[1] = (_Float16)a.y; r[2] = (_Float16)a.z; r[3] = (_Float16)a.w;
    r[4] = (_Float16)b.x; r[5] = (_Float16)b.y; r[6] = (_Float16)b.z; r[7] = (_Float16)b.w;
    return r;
}

__device__ inline h4_t load4f_to_h4(const float* p) {
    float4 a = *(const float4*)p;
    h4_t r;
    r[0] = (_Float16)a.x; r[1] = (_Float16)a.y; r[2] = (_Float16)a.z; r[3] = (_Float16)a.w;
    return r;
}

__device__ inline float dot8h(h8_t a, h8_t b, float s) {
    s = __builtin_amdgcn_fdot2(__builtin_shufflevector(a, a, 0, 1),
                               __builtin_shufflevector(b, b, 0, 1), s, false);
    s = __builtin_amdgcn_fdot2(__builtin_shufflevector(a, a, 2, 3),
                               __builtin_shufflevector(b, b, 2, 3), s, false);
    s = __builtin_amdgcn_fdot2(__builtin_shufflevector(a, a, 4, 5),
                               __builtin_shufflevector(b, b, 4, 5), s, false);
    s = __builtin_amdgcn_fdot2(__builtin_shufflevector(a, a, 6, 7),
                               __builtin_shufflevector(b, b, 6, 7), s, false);
    return s;
}

__device__ inline float dot4h(h4_t a, h4_t b, float s) {
    s = __builtin_amdgcn_fdot2(__builtin_shufflevector(a, a, 0, 1),
                               __builtin_shufflevector(b, b, 0, 1), s, false);
    s = __builtin_amdgcn_fdot2(__builtin_shufflevector(a, a, 2, 3),
                               __builtin_shufflevector(b, b, 2, 3), s, false);
    return s;
}

__device__ inline float elu1(float v) { return v > 0.f ? v : __expf(v) - 1.f; }

struct MA {
    const float* x;
    const float* eattr;
    const int* ei;
    const float *w1l, *b1l, *w1r, *b1r, *w1e, *att1, *bias1;
    const float *w2l, *b2l, *w2r, *b2r, *w2e, *att2, *bias2;
    const float *wc, *bc;
    float* out;
    _Float16 *xh, *xl1h, *xr1h, *h1h, *xl2h, *xr2h;
    _Float16 *p1l, *p1r, *p2l, *p2r;
    int *deg, *offb;
    unsigned* parth;      // SB x NBUK_PAD partial hist; after colscan: within-bucket excl prefix
    unsigned *tstart, *tot;
    unsigned* smeanq;
    unsigned* tmp;        // 4B packed: src[0:15] | q[16:23] | loc[24:29]
    float* part;
    unsigned* edges;
    int N, E, NW, NBK, CE;
    float invE;
};

// ---- phase helpers -------------------------------------------------------

__device__ inline void phase_packw(const MA& a, int g) {
    const float* W;
    _Float16* P;
    int M, lg;
    if (g < 2048)      { W = a.w1l; P = a.p1l; M = 128; lg = g; }
    else if (g < 4096) { W = a.w1r; P = a.p1r; M = 128; lg = g - 2048; }
    else if (g < 5120) { W = a.w2l; P = a.p2l; M = 64;  lg = g - 4096; }
    else               { W = a.w2r; P = a.p2r; M = 64;  lg = g - 5120; }
    int ln = lg & 63;
    int s = (lg >> 6) & 3;
    int tt = lg >> 8;
    int m = ln & 15, quad = ln >> 4;
    h8_t v;
#pragma unroll
    for (int j = 0; j < 8; ++j)
        v[j] = (_Float16)W[(size_t)(s * 32 + quad * 8 + j) * M + tt * 16 + m];
    *(h8_t*)(P + (size_t)lg * 8) = v;
}

template <int NT>
__device__ inline void phase_mm_tile(const MA& a, const _Float16* X, int rt, int lane,
                                     const _Float16* Pl, const float* bl, _Float16* Yl,
                                     const _Float16* Pr, const float* br, _Float16* Yr) {
    int nrow = lane & 15, quad = lane >> 4;
    int row = rt * 16 + nrow;
    if (row >= a.N) return;
    const _Float16* xp = X + (size_t)row * 128 + quad * 8;
    h8_t bf0 = *(const h8_t*)(xp);
    h8_t bf1 = *(const h8_t*)(xp + 32);
    h8_t bf2 = *(const h8_t*)(xp + 64);
    h8_t bf3 = *(const h8_t*)(xp + 96);
#pragma unroll
    for (int w = 0; w < 2; ++w) {
        const _Float16* P = w ? Pr : Pl;
        const float* bias = w ? br : bl;
        _Float16* Y = w ? Yr : Yl;
#pragma unroll
        for (int t2 = 0; t2 < NT; ++t2) {
            f4_t acc = {0.f, 0.f, 0.f, 0.f};
            const _Float16* pb = P + (size_t)t2 * 2048 + (size_t)lane * 8;
            acc = __builtin_amdgcn_mfma_f32_16x16x32_f16(*(const h8_t*)pb, bf0, acc, 0, 0, 0);
            acc = __builtin_amdgcn_mfma_f32_16x16x32_f16(*(const h8_t*)(pb + 512), bf1, acc, 0, 0, 0);
            acc = __builtin_amdgcn_mfma_f32_16x16x32_f16(*(const h8_t*)(pb + 1024), bf2, acc, 0, 0, 0);
            acc = __builtin_amdgcn_mfma_f32_16x16x32_f16(*(const h8_t*)(pb + 1536), bf3, acc, 0, 0, 0);
            float4 bv = *(const float4*)(bias + t2 * 16 + quad * 4);
            h4_t o;
            o[0] = (_Float16)(acc[0] + bv.x);
            o[1] = (_Float16)(acc[1] + bv.y);
            o[2] = (_Float16)(acc[2] + bv.z);
            o[3] = (_Float16)(acc[3] + bv.w);
            *(h4_t*)(Y + (size_t)row * (NT * 16) + t2 * 16 + quad * 4) = o;
        }
    }
}

// ---- k_pre: x->fp16, eattr partials, per-chunk bucket hist; tail blocks
// pack weights -------------------------------------------------------------

__global__ __launch_bounds__(256) void k_pre(MA a) {
    if (blockIdx.x >= PRE_BLOCKS) {
        int g = (blockIdx.x - PRE_BLOCKS) * 256 + threadIdx.x;
        if (g < 6144) phase_packw(a, g);
        return;
    }
    __shared__ unsigned bh[NBUK_PAD];
    __shared__ float sd[4];
    int tx = threadIdx.x;
    for (int j = tx; j < NBUK_PAD; j += 256) bh[j] = 0u;

    int t = blockIdx.x * 256 + tx;
    const int stride = PRE_BLOCKS * 256;
    int nchunk = (a.N * 128) >> 3;
    for (int i = t; i < nchunk; i += stride) {
        h8_t v = load8f_to_h8(a.x + (size_t)i * 8);
        *(h8_t*)(a.xh + (size_t)i * 8) = v;
    }
    float s = 0.f;
    for (int i = t; i < a.E; i += stride) s += a.eattr[i];
    for (int o = 1; o < 64; o <<= 1) s += __shfl_xor(s, o, 64);
    if ((tx & 63) == 0) sd[tx >> 6] = s;
    __syncthreads();  // bh zeroed + sd published
    if (tx == 0) a.part[blockIdx.x] = sd[0] + sd[1] + sd[2] + sd[3];

    // chunked bucket histogram (must match k_scatter's chunking exactly)
    int e0 = blockIdx.x * a.CE, e1 = min(e0 + a.CE, a.E);
    for (int e = e0 + tx; e < e1; e += 256)
        atomicAdd(&bh[((unsigned)a.ei[a.E + e]) >> 6], 1u);
    __syncthreads();
    for (int j = tx; j < NBUK_PAD; j += 256)
        a.parth[(size_t)blockIdx.x * NBUK_PAD + j] = bh[j];
}

// ---- k_colscan: per bucket, scan the 512 block-partials (column of parth)
// -> within-bucket exclusive prefix (in place) + bucket total. No cross-
// bucket dependency, no lookback (R5 post-mortem: serial lookback walk over
// 782 blocks was the hidden ~80us cost). ----------------------------------

__global__ __launch_bounds__(512, 1) void k_colscan(MA a) {
    __shared__ unsigned lds[512];
    int tx = threadIdx.x;
    int b = blockIdx.x;
    unsigned v = a.parth[(size_t)tx * NBUK_PAD + b];
    lds[tx] = v;
    __syncthreads();
    for (int o = 1; o < 512; o <<= 1) {
        unsigned u = (tx >= o) ? lds[tx - o] : 0u;
        __syncthreads();
        lds[tx] += u;
        __syncthreads();
    }
    a.parth[(size_t)tx * NBUK_PAD + b] = lds[tx] - v;  // within-bucket exclusive
    if (tx == 511) a.tot[b] = lds[511];
}

// ---- k_scan2: single block scans the <=1024 bucket totals -> tstart[],
// and reduces the eattr-mean partials -> smeanq. Tiny (~3us). --------------

__global__ __launch_bounds__(1024, 1) void k_scan2(MA a) {
    __shared__ unsigned lds[1024];
    __shared__ float sd[16];
    int tx = threadIdx.x;
    unsigned v = (tx < a.NBK) ? a.tot[tx] : 0u;
    lds[tx] = v;
    float s = (tx < PRE_BLOCKS) ? a.part[tx] : 0.f;
    for (int o = 1; o < 64; o <<= 1) s += __shfl_xor(s, o, 64);
    if ((tx & 63) == 0) sd[tx >> 6] = s;
    __syncthreads();
    for (int o = 1; o < 1024; o <<= 1) {
        unsigned u = (tx >= o) ? lds[tx - o] : 0u;
        __syncthreads();
        lds[tx] += u;
        __syncthreads();
    }
    if (tx < a.NBK) a.tstart[tx] = lds[tx] - v;
    if (tx == 0) {
        float m = 0.f;
#pragma unroll
        for (int k = 0; k < 16; ++k) m += sd[k];
        a.smeanq[0] = (unsigned)__float2int_rn(m * a.invE * 255.f);
    }
}

// ---- k_scatter: blocks [0,NW) = layer-1 GEMM; blocks [NW,NW+SB) scatter
// edges into coarse-bucket regions of tmp via LDS cursors (zero global
// atomics). cur = tstart[bucket] + within-bucket chunk base. --------------

__global__ __launch_bounds__(256) void k_scatter(MA a) {
    int bid = blockIdx.x;
    if (bid < a.NW) {
        int wid = bid * 4 + (threadIdx.x >> 6);
        int ntile = (a.N + 15) / 16;
        if (wid < ntile)
            phase_mm_tile<8>(a, a.xh, wid, threadIdx.x & 63,
                             a.p1l, a.b1l, a.xl1h, a.p1r, a.b1r, a.xr1h);
        return;
    }
    __shared__ unsigned cur[NBUK_PAD];
    int s = bid - a.NW;
    int tx = threadIdx.x;
    for (int j = tx; j < NBUK_PAD; j += 256)
        cur[j] = a.parth[(size_t)s * NBUK_PAD + j] + a.tstart[j];
    __syncthreads();
    int e0 = s * a.CE, e1 = min(e0 + a.CE, a.E);
    for (int e = e0 + tx; e < e1; e += 256) {
        int d = a.ei[a.E + e];
        unsigned src = (unsigned)a.ei[e];
        unsigned q = (unsigned)__float2int_rn(a.eattr[e] * 255.f);
        unsigned pos = atomicAdd(&cur[d >> 6], 1u);
        a.tmp[pos] = src | (q << 16) | ((unsigned)(d & 63) << 24);
    }
}

// ---- k_fine: per bucket (64 contiguous nodes): local hist + wave scan ->
// exact CSR offsets (no global scan needed), write self-loops + edges. ----

__global__ __launch_bounds__(256) void k_fine(MA a) {
    __shared__ int hist[64];
    __shared__ unsigned cur[64];
    __shared__ unsigned sm;
    int b = blockIdx.x;
    int tx = threadIdx.x;
    int n0 = b << 6;
    int nn = min(64, a.N - n0);
    unsigned ts = a.tstart[b], T = a.tot[b];
    if (tx < 64) hist[tx] = 0;
    if (tx == 0) sm = a.smeanq[0];
    __syncthreads();
    for (unsigned i = tx; i < T; i += 256) {
        unsigned v = a.tmp[ts + i];
        atomicAdd(&hist[(int)(v >> 24)], 1);
    }
    __syncthreads();
    if (tx < 64) {
        int deg1 = hist[tx] + 1;
        int vsc = deg1;
#pragma unroll
        for (int o = 1; o < 64; o <<= 1) {
            int u = __shfl_up(vsc, o, 64);
            if (tx >= o) vsc += u;
        }
        int off = (int)ts + n0 + (vsc - deg1);  // ts + 64*b accounts for prior self-loops
        if (tx < nn) {
            a.offb[n0 + tx] = off;
            a.deg[n0 + tx] = deg1;
            a.edges[off] = (unsigned)(n0 + tx) | (sm << 24);
        }
        cur[tx] = (unsigned)(off + 1);
    }
    __syncthreads();
    for (unsigned i = tx; i < T; i += 256) {
        unsigned v = a.tmp[ts + i];
        int loc = (int)(v >> 24);
        unsigned pos = atomicAdd(&cur[loc], 1u);
        a.edges[pos] = (v & 0xFFFFu) | (((v >> 16) & 0xFFu) << 24);
    }
}

// ---- k_node1: layer-1 node pass. 16 lanes per node, software-pipelined
// double buffer (R5: small win, kept). -------------------------------------

__global__ __launch_bounds__(256) void k_node1(MA a) {
    int tid = threadIdx.x;
    int q = tid & 15;
    int node = blockIdx.x * 16 + (tid >> 4);
    if (node >= a.N) return;
    unsigned cb = (unsigned)(q * 16);  // byte offset of this lane's 8 halves

    h8_t xrv = *(const h8_t*)((const char*)a.xr1h + ((unsigned)node << 8) + cb);
    h8_t wev = load8f_to_h8(a.w1e + q * 8);
    h8_t atv = load8f_to_h8(a.att1 + q * 8);
    const unsigned* ep = a.edges + a.offb[node];
    int deg1 = a.deg[node];
    int last = deg1 - 1;
    const char* xb = (const char*)a.xl1h;

    float l = 0.f;
    f8_t acc = {0.f, 0.f, 0.f, 0.f, 0.f, 0.f, 0.f, 0.f};

    auto GA = [&](unsigned p) -> h8_t {
        return *(const h8_t*)(xb + (((p & 0x00FFFFFFu) << 8) | cb));
    };
    auto LOADG = [&](int i, unsigned& p0, unsigned& p1, unsigned& p2, unsigned& p3,
                     h8_t& x0, h8_t& x1, h8_t& x2, h8_t& x3) {
        p0 = ep[i];
        p1 = ep[min(i + 1, last)];
        p2 = ep[min(i + 2, last)];
        p3 = ep[min(i + 3, last)];
        x0 = GA(p0); x1 = GA(p1); x2 = GA(p2); x3 = GA(p3);
    };
    auto COMPG = [&](int i, unsigned p0, unsigned p1, unsigned p2, unsigned p3,
                     h8_t x0, h8_t x1, h8_t x2, h8_t x3) {
        float e0 = (float)(p0 >> 24) * (1.f / 255.f);
        float e1 = (float)(p1 >> 24) * (1.f / 255.f);
        float e2 = (float)(p2 >> 24) * (1.f / 255.f);
        float e3 = (float)(p3 >> 24) * (1.f / 255.f);
        h8_t z0 = x0 + xrv + wev * (_Float16)e0;
        z0 = __builtin_elementwise_max(z0, z0 * (_Float16)0.2f);
        float sc0 = dot8h(z0, atv, 0.f);
        h8_t z1 = x1 + xrv + wev * (_Float16)e1;
        z1 = __builtin_elementwise_max(z1, z1 * (_Float16)0.2f);
        float sc1 = dot8h(z1, atv, 0.f);
        h8_t z2 = x2 + xrv + wev * (_Float16)e2;
        z2 = __builtin_elementwise_max(z2, z2 * (_Float16)0.2f);
        float sc2 = dot8h(z2, atv, 0.f);
        h8_t z3 = x3 + xrv + wev * (_Float16)e3;
        z3 = __builtin_elementwise_max(z3, z3 * (_Float16)0.2f);
        float sc3 = dot8h(z3, atv, 0.f);
        sc0 += __shfl_xor(sc0, 1, 64); sc0 += __shfl_xor(sc0, 2, 64);
        sc1 += __shfl_xor(sc1, 1, 64); sc1 += __shfl_xor(sc1, 2, 64);
        sc2 += __shfl_xor(sc2, 1, 64); sc2 += __shfl_xor(sc2, 2, 64);
        sc3 += __shfl_xor(sc3, 1, 64); sc3 += __shfl_xor(sc3, 2, 64);
        float pA = __expf(fminf(sc0, 60.f));
        float pB = (i + 1 < deg1) ? __expf(fminf(sc1, 60.f)) : 0.f;
        float pC = (i + 2 < deg1) ? __expf(fminf(sc2, 60.f)) : 0.f;
        float pD = (i + 3 < deg1) ? __expf(fminf(sc3, 60.f)) : 0.f;
        l += (pA + pB) + (pC + pD);
#pragma unroll
        for (int k = 0; k < 8; ++k)
            acc[k] = fmaf(pA, (float)x0[k],
                     fmaf(pB, (float)x1[k],
                     fmaf(pC, (float)x2[k], fmaf(pD, (float)x3[k], acc[k]))));
    };

    unsigned pa0, pa1, pa2, pa3, pb0, pb1, pb2, pb3;
    h8_t xa0, xa1, xa2, xa3, xb0, xb1, xb2, xb3;
    LOADG(0, pa0, pa1, pa2, pa3, xa0, xa1, xa2, xa3);
    for (int i = 0; i < deg1; i += 8) {
        if (i + 4 < deg1) LOADG(i + 4, pb0, pb1, pb2, pb3, xb0, xb1, xb2, xb3);
        COMPG(i, pa0, pa1, pa2, pa3, xa0, xa1, xa2, xa3);
        if (i + 8 < deg1) LOADG(i + 8, pa0, pa1, pa2, pa3, xa0, xa1, xa2, xa3);
        if (i + 4 < deg1) COMPG(i + 4, pb0, pb1, pb2, pb3, xb0, xb1, xb2, xb3);
    }

    float inv = 1.f / l;
    float4 b0 = *(const float4*)(a.bias1 + q * 8);
    float4 b1 = *(const float4*)(a.bias1 + q * 8 + 4);
    float bb[8] = {b0.x, b0.y, b0.z, b0.w, b1.x, b1.y, b1.z, b1.w};
    h8_t o;
#pragma unroll
    for (int k = 0; k < 8; ++k) o[k] = (_Float16)elu1(fmaf(acc[k], inv, bb[k]));
    *(h8_t*)((char*)a.h1h + ((unsigned)node << 8) + cb) = o;
}

// ---- k_mm4: layer-2 MFMA GEMM --------------------------------------------

__global__ __launch_bounds__(256) void k_mm4(MA a) {
    int wid = blockIdx.x * 4 + (threadIdx.x >> 6);
    int ntile = (a.N + 15) / 16;
    if (wid >= ntile) return;
    phase_mm_tile<4>(a, a.h1h, wid, threadIdx.x & 63,
                     a.p2l, a.b2l, a.xl2h, a.p2r, a.b2r, a.xr2h);
}

// ---- k_node2: layer-2 node pass + fused classifier (R3 form; R5's
// pipelined variant regressed -- VGPR/occupancy cost with no latency to
// hide at this arithmetic intensity). --------------------------------------

__global__ __launch_bounds__(256) void k_node2(MA a) {
    __shared__ float h2s[16][33];
    int tid = threadIdx.x;
    int lane = tid & 63;
    int wib = tid >> 6;
    int sub = lane >> 4;
    int r = lane & 15;
    int nloc = wib * 4 + sub;
    int node = blockIdx.x * 16 + nloc;
    int c0 = r * 4;

    if (node < a.N) {
        h4_t xrv = *(const h4_t*)(a.xr2h + (size_t)node * 64 + c0);
        h4_t wev = load4f_to_h4(a.w2e + c0);
        h4_t atv = load4f_to_h4(a.att2 + c0);
        const unsigned* ep = a.edges + a.offb[node];
        int deg1 = a.deg[node];
        int last = deg1 - 1;
        const char* xb = (const char*)a.xl2h;
        unsigned cb = (unsigned)(c0 * 2);
        float l = 0.f;
        float acc[4] = {0.f, 0.f, 0.f, 0.f};
        for (int i = 0; i < deg1; i += 4) {
            unsigned p[4];
            h4_t xv[4];
#pragma unroll
            for (int j = 0; j < 4; ++j) p[j] = ep[min(i + j, last)];
#pragma unroll
            for (int j = 0; j < 4; ++j)
                xv[j] = *(const h4_t*)(xb + (((p[j] & 0x00FFFFFFu) << 7) | cb));
#pragma unroll
            for (int j = 0; j < 4; ++j) {
                float ea = (float)(p[j] >> 24) * (1.f / 255.f);
                h4_t z = xv[j] + xrv + wev * (_Float16)ea;
                z = __builtin_elementwise_max(z, z * (_Float16)0.2f);
                float sc = dot4h(z, atv, 0.f);
                sc += __shfl_xor(sc, 1, 64);
                sc += __shfl_xor(sc, 2, 64);
                sc += __shfl_xor(sc, 4, 64);
                float pp = (i + j < deg1) ? __expf(fminf(sc, 60.f)) : 0.f;
                l += pp;
#pragma unroll
                for (int k = 0; k < 4; ++k) acc[k] = fmaf(pp, (float)xv[j][k], acc[k]);
            }
        }
        float inv = 1.f / l;
#pragma unroll
        for (int k = 0; k < 4; ++k) {
            float norm = acc[k] * inv;
            float other = __shfl_xor(norm, 8, 64);
            float v = 0.5f * (norm + other);
            if (r < 8) h2s[nloc][c0 + k] = elu1(v + a.bias2[c0 + k]);
        }
    }
    __syncthreads();
    if (tid < 128) {
        int n = tid >> 3, j = tid & 7;
        int gnode = blockIdx.x * 16 + n;
        if (gnode < a.N) {
            float acc = a.bc[j];
#pragma unroll 8
            for (int d = 0; d < 32; ++d) acc = fmaf(h2s[n][d], a.wc[d * 8 + j], acc);
            a.out[(size_t)gnode * 8 + j] = acc;
        }
    }
}

// ---- launch --------------------------------------------------------------

extern "C" void kernel_launch(void* const* d_in, const int* in_sizes, int n_in,
                              void* d_out, int out_size, void* d_ws, size_t ws_size,
                              hipStream_t stream) {
    const int N = in_sizes[0] / 128;
    const int E = in_sizes[2];
    const int tot = E + N;

    char* ws = (char*)d_ws;
    size_t o = 0;
    auto alloc = [&](size_t bytes) -> void* {
        void* p = ws + o;
        o += (bytes + 255) & ~(size_t)255;
        return p;
    };
    MA a;
    a.x     = (const float*)d_in[0];
    a.ei    = (const int*)d_in[1];
    a.eattr = (const float*)d_in[2];
    a.w1l = (const float*)d_in[3];  a.b1l = (const float*)d_in[4];
    a.w1r = (const float*)d_in[5];  a.b1r = (const float*)d_in[6];
    a.w1e = (const float*)d_in[7];  a.att1 = (const float*)d_in[8];
    a.bias1 = (const float*)d_in[9];
    a.w2l = (const float*)d_in[10]; a.b2l = (const float*)d_in[11];
    a.w2r = (const float*)d_in[12]; a.b2r = (const float*)d_in[13];
    a.w2e = (const float*)d_in[14]; a.att2 = (const float*)d_in[15];
    a.bias2 = (const float*)d_in[16];
    a.wc = (const float*)d_in[17];  a.bc = (const float*)d_in[18];
    a.out = (float*)d_out;

    a.xh   = (_Float16*)alloc((size_t)N * 128 * 2);
    a.xl1h = (_Float16*)alloc((size_t)N * 128 * 2);
    a.xr1h = (_Float16*)alloc((size_t)N * 128 * 2);
    a.h1h  = (_Float16*)alloc((size_t)N * 128 * 2);
    a.xl2h = (_Float16*)alloc((size_t)N * 64 * 2);
    a.xr2h = (_Float16*)alloc((size_t)N * 64 * 2);
    a.p1l  = (_Float16*)alloc(128 * 128 * 2);
    a.p1r  = (_Float16*)alloc(128 * 128 * 2);
    a.p2l  = (_Float16*)alloc(128 * 64 * 2);
    a.p2r  = (_Float16*)alloc(128 * 64 * 2);
    a.deg  = (int*)alloc((size_t)N * 4);
    a.offb = (int*)alloc((size_t)N * 4);
    a.parth  = (unsigned*)alloc((size_t)SB * NBUK_PAD * 4);
    a.tstart = (unsigned*)alloc(1024 * 4);
    a.tot    = (unsigned*)alloc(1024 * 4);
    a.smeanq = (unsigned*)alloc(256);
    a.part   = (float*)alloc(PRE_BLOCKS * 4);
    a.tmp    = (unsigned*)alloc((size_t)E * 4);
    a.edges  = (unsigned*)alloc((size_t)tot * 4);
    a.N = N;
    a.E = E;
    a.NW = (N + 63) / 64;
    a.NBK = (N + 63) >> 6;
    a.CE = (E + SB - 1) / SB;
    a.invE = 1.0f / (float)E;

    k_pre<<<PRE_BLOCKS + 24, 256, 0, stream>>>(a);
    k_colscan<<<a.NBK, 512, 0, stream>>>(a);
    k_scan2<<<1, 1024, 0, stream>>>(a);
    k_scatter<<<a.NW + SB, 256, 0, stream>>>(a);
    k_fine<<<a.NBK, 256, 0, stream>>>(a);
    k_node1<<<(N + 15) / 16, 256, 0, stream>>>(a);
    k_mm4<<<(N + 63) / 64, 256, 0, stream>>>(a);
    k_node2<<<(N + 15) / 16, 256, 0, stream>>>(a);
}